// Round 1
// baseline (253.359 us; speedup 1.0000x reference)
//
#include <hip/hip_runtime.h>

// Problem constants (match reference)
#define NV 300000
#define FDIM 64
#define KN 9

// One wave (64 lanes) per vertex; lane == feature index.
// 4 waves / 256-thread block -> 4 vertices per block.
__global__ __launch_bounds__(256) void aflow_kernel(
    const float* __restrict__ lattice_values,  // (N, F)
    const float* __restrict__ hidden_state,    // (N, F)
    const float* __restrict__ bias,            // (F,)
    const float* __restrict__ alpha_p,         // scalar
    const float* __restrict__ beta_p,          // scalar
    const int*   __restrict__ neighbor_idx,    // (N, K)
    float* __restrict__ out_aflow,             // (N, F)
    float* __restrict__ out_weights,           // (N, K)
    float* __restrict__ out_idx)               // (N, K) as float values
{
    const int lane = threadIdx.x & 63;
    const int wave = threadIdx.x >> 6;
    const int n = blockIdx.x * 4 + wave;
    if (n >= NV) return;

    const float alpha = *alpha_p;
    const float beta  = *beta_p;

    // my feature of the center row
    const float lv = lattice_values[n * FDIM + lane];

    // lanes 0..8 hold the 9 neighbor indices
    int myidx = -1;
    if (lane < KN) myidx = neighbor_idx[n * KN + lane];

    float neigh[KN];
    float dist[KN];

    #pragma unroll
    for (int k = 0; k < KN; ++k) {
        const int idx = __shfl(myidx, k);          // broadcast idx_k to all lanes
        float h = 0.0f;
        if (idx >= 0) h = hidden_state[idx * FDIM + lane];  // coalesced 256B row
        neigh[k] = h;
        float d = h - lv;
        float s = d * d;
        // 64-lane butterfly reduce; result broadcast to all lanes
        #pragma unroll
        for (int off = 32; off; off >>= 1) s += __shfl_xor(s, off);
        dist[k] = (idx >= 0) ? sqrtf(s) : 0.0f;   // invalid neighbors contribute 0
    }

    float dsum = 0.0f;
    #pragma unroll
    for (int k = 0; k < KN; ++k) dsum += dist[k];
    const float inv = 1.0f / dsum;                // matches reference (no eps)

    float acc  = bias[lane];
    float wout = 0.0f;
    #pragma unroll
    for (int k = 0; k < KN; ++k) {
        const int idx = __shfl(myidx, k);
        const float dn = dist[k] * inv;
        float w = (alpha - fminf(dn, alpha)) * beta;
        w = (idx >= 0) ? w : 0.0f;                // weights *= valid
        acc += neigh[k] * w;
        if (lane == k) wout = w;                  // lane k keeps weight k
    }

    out_aflow[n * FDIM + lane] = acc;
    if (lane < KN) {
        out_weights[n * KN + lane] = wout;
        out_idx[n * KN + lane]     = (float)myidx; // idx passthrough as f32 values
    }
}

extern "C" void kernel_launch(void* const* d_in, const int* in_sizes, int n_in,
                              void* d_out, int out_size, void* d_ws, size_t ws_size,
                              hipStream_t stream) {
    const float* lattice_values = (const float*)d_in[0];
    const float* hidden_state   = (const float*)d_in[1];
    const float* bias           = (const float*)d_in[2];
    const float* alpha          = (const float*)d_in[3];
    const float* beta           = (const float*)d_in[4];
    const int*   neighbor_idx   = (const int*)d_in[5];

    float* out = (float*)d_out;
    float* out_aflow   = out;                      // N*F
    float* out_weights = out + (size_t)NV * FDIM;  // N*K
    float* out_idx     = out_weights + (size_t)NV * KN; // N*K

    const int blocks = (NV + 3) / 4; // 4 vertices per 256-thread block
    aflow_kernel<<<blocks, 256, 0, stream>>>(
        lattice_values, hidden_state, bias, alpha, beta, neighbor_idx,
        out_aflow, out_weights, out_idx);
}

// Round 2
// 123.836 us; speedup vs baseline: 2.0459x; 2.0459x over previous
//
#include <hip/hip_runtime.h>

// Problem constants (match reference)
#define NV 300000
#define FDIM 64
#define KN 9

// 16-lane sub-wave per vertex; lane handles 4 features (float4).
// 4 vertices per wave, 16 per 256-thread block. NV % 16 == 0 -> no tail.
__device__ __forceinline__ float row16_reduce_add(float x) {
    // butterfly over 16 lanes, pure-VALU DPP; result broadcast to all 16
    int t;
    t = __builtin_amdgcn_update_dpp(0, __float_as_int(x), 0xB1, 0xF, 0xF, true); // quad_perm [1,0,3,2] (xor 1)
    x += __int_as_float(t);
    t = __builtin_amdgcn_update_dpp(0, __float_as_int(x), 0x4E, 0xF, 0xF, true); // quad_perm [2,3,0,1] (xor 2)
    x += __int_as_float(t);
    t = __builtin_amdgcn_update_dpp(0, __float_as_int(x), 0x141, 0xF, 0xF, true); // row_half_mirror (pairs quads in 8)
    x += __int_as_float(t);
    t = __builtin_amdgcn_update_dpp(0, __float_as_int(x), 0x140, 0xF, 0xF, true); // row_mirror (pairs halves in 16)
    x += __int_as_float(t);
    return x;
}

__global__ __launch_bounds__(256) void aflow_kernel(
    const float* __restrict__ lattice_values,  // (N, F)
    const float* __restrict__ hidden_state,    // (N, F)
    const float* __restrict__ bias,            // (F,)
    const float* __restrict__ alpha_p,         // scalar
    const float* __restrict__ beta_p,          // scalar
    const int*   __restrict__ neighbor_idx,    // (N, K)
    float* __restrict__ out_aflow,             // (N, F)
    float* __restrict__ out_weights,           // (N, K)
    float* __restrict__ out_idx)               // (N, K) as float values
{
    const int lane = threadIdx.x & 63;
    const int wave = threadIdx.x >> 6;
    const int sub  = lane >> 4;   // which vertex within the wave
    const int sl   = lane & 15;   // sub-lane: feature group (4 floats)
    const int n    = (blockIdx.x * 4 + wave) * 4 + sub;

    const float alpha = *alpha_p;
    const float beta  = *beta_p;

    const float4* __restrict__ lv4 = (const float4*)lattice_values;
    const float4* __restrict__ hs4 = (const float4*)hidden_state;

    const float4 lv = lv4[n * 16 + sl];

    // lanes sl<9 of each sub-wave hold that vertex's 9 neighbor indices
    int myidx = -1;
    if (sl < KN) myidx = neighbor_idx[n * KN + sl];

    const int base = lane & 48;  // first lane of my sub-wave

    // --- phase 1: broadcast indices + issue all 9 gathers (MLP) ---
    int   idxk[KN];
    float4 neigh[KN];
    int vbits = 0;
    #pragma unroll
    for (int k = 0; k < KN; ++k) {
        idxk[k] = __shfl(myidx, base + k);       // sub-wave-uniform
        vbits |= (idxk[k] >= 0) ? (1 << k) : 0;
    }
    #pragma unroll
    for (int k = 0; k < KN; ++k) {
        const int ic = idxk[k] >= 0 ? idxk[k] : 0;  // branch-free clamp
        neigh[k] = hs4[ic * 16 + sl];               // coalesced 256B / sub-wave
    }

    // --- phase 2: distances (DPP reduce over 16 lanes) ---
    float dist[KN];
    #pragma unroll
    for (int k = 0; k < KN; ++k) {
        const float4 h = neigh[k];
        const float dx = h.x - lv.x, dy = h.y - lv.y, dz = h.z - lv.z, dw = h.w - lv.w;
        float s = dx*dx;
        s = fmaf(dy, dy, s);
        s = fmaf(dz, dz, s);
        s = fmaf(dw, dw, s);
        s = row16_reduce_add(s);
        dist[k] = ((vbits >> k) & 1) ? sqrtf(s) : 0.0f;  // invalid -> 0
    }

    float dsum = 0.0f;
    #pragma unroll
    for (int k = 0; k < KN; ++k) dsum += dist[k];
    const float inv = 1.0f / dsum;   // matches reference (no eps)

    // --- phase 3: weights + aggregation ---
    float4 acc = ((const float4*)bias)[sl];
    float wout = 0.0f;
    #pragma unroll
    for (int k = 0; k < KN; ++k) {
        const float dn = dist[k] * inv;
        float w = (alpha - fminf(dn, alpha)) * beta;
        w = ((vbits >> k) & 1) ? w : 0.0f;
        const float4 h = neigh[k];  // invalid k: w==0 so garbage row is harmless
        acc.x = fmaf(h.x, w, acc.x);
        acc.y = fmaf(h.y, w, acc.y);
        acc.z = fmaf(h.z, w, acc.z);
        acc.w = fmaf(h.w, w, acc.w);
        if (sl == k) wout = w;      // lane k of sub-wave keeps weight k
    }

    ((float4*)out_aflow)[n * 16 + sl] = acc;
    if (sl < KN) {
        out_weights[n * KN + sl] = wout;
        out_idx[n * KN + sl]     = (float)myidx;  // passthrough as f32 values
    }
}

extern "C" void kernel_launch(void* const* d_in, const int* in_sizes, int n_in,
                              void* d_out, int out_size, void* d_ws, size_t ws_size,
                              hipStream_t stream) {
    const float* lattice_values = (const float*)d_in[0];
    const float* hidden_state   = (const float*)d_in[1];
    const float* bias           = (const float*)d_in[2];
    const float* alpha          = (const float*)d_in[3];
    const float* beta           = (const float*)d_in[4];
    const int*   neighbor_idx   = (const int*)d_in[5];

    float* out = (float*)d_out;
    float* out_aflow   = out;                           // N*F
    float* out_weights = out + (size_t)NV * FDIM;       // N*K
    float* out_idx     = out_weights + (size_t)NV * KN; // N*K

    const int blocks = NV / 16;  // 16 vertices per 256-thread block (NV%16==0)
    aflow_kernel<<<blocks, 256, 0, stream>>>(
        lattice_values, hidden_state, bias, alpha, beta, neighbor_idx,
        out_aflow, out_weights, out_idx);
}